// Round 6
// baseline (118.056 us; speedup 1.0000x reference)
//
#include <hip/hip_runtime.h>
#include <hip/hip_bf16.h>
#include <stdint.h>

// InfPamAtt fused attention, MI355X/gfx950.  Round 6: SAFE build.
// All inline asm removed (C-level bf16 RNE pack, __shfl_xor repack);
// LDS staging is single-buffer + __syncthreads-bracketed (hardware-ordered,
// no TBAA/fence reliance). Failure modes now diagnostic:
//   pass -> asm/fence was the bug; finite-wrong -> fragment layout; NaN -> qkv/MFMA.
//   qkv_k : MFMA 1x1-convs -> q/k packed bf16 rows (+zero pad), v^T bf16.
//   attn_k: grid (b,4 x mtile,128 of 32 q-rows); block 256 = 4 waves.
//           Wave w: same 32 q-rows, disjoint keys [w*1024,(w+1)*1024) in 16
//           chunks of 64. Per chunk: reg-prefetch next; S^T = mfma(K,Q);
//           p = exp2(clamp); shfl repack to PV B-frag; acc += mfma(V^T,P^T).
//           End: publish partials in LDS, cross-wave reduce, out = g*o/rs + x.
// Workspace: qp 512K | kp 512K | vb 2M = 3.07 MB.

typedef float    f32x16 __attribute__((ext_vector_type(16)));
typedef short    bf16x8 __attribute__((ext_vector_type(8)));
typedef unsigned int   u32;
typedef unsigned short u16;
typedef u32 u32x4 __attribute__((ext_vector_type(4)));

#define LOG2E 1.4426950408889634f

// f32 -> bf16 bits (round-to-nearest-even), result in low 16 bits. Pure C.
__device__ __forceinline__ u32 bfr(float f){
  u32 u = __float_as_uint(f);
  return (u + 0x7FFFu + ((u >> 16) & 1u)) >> 16;
}
__device__ __forceinline__ u32 pk2(float lo, float hi){
  return bfr(lo) | (bfr(hi) << 16);
}
__device__ __forceinline__ bf16x8 mk_frag(u32 a, u32 b, u32 c, u32 d){
  union { u32 u[4]; bf16x8 v; } t; t.u[0]=a; t.u[1]=b; t.u[2]=c; t.u[3]=d; return t.v;
}
__device__ __forceinline__ bf16x8 pack8(float t0,float t1,float t2,float t3,
                                        float t4,float t5,float t6,float t7){
  return mk_frag(pk2(t0,t1), pk2(t2,t3), pk2(t4,t5), pk2(t6,t7));
}
__device__ __forceinline__ f32x16 mfma32(bf16x8 a, bf16x8 b, f32x16 c){
  return __builtin_amdgcn_mfma_f32_32x32x16_bf16(a, b, c, 0, 0, 0);
}
__device__ __forceinline__ bf16x8 lds_frag(const char* p){
  union { u32x4 u; bf16x8 f; } t; t.u = *(const u32x4*)p; return t.f;
}
#if __has_builtin(__builtin_amdgcn_exp2f)
#define EXP2(x) __builtin_amdgcn_exp2f(x)
#else
#define EXP2(x) exp2f(x)
#endif
// Two-sided clamp: sanitizes NaN and bounds exp2 to [2^-80, 2^80] -> rowsum
// strictly positive & finite. Keeps failure modes diagnostic.
__device__ __forceinline__ float sclamp(float s){
  return fminf(fmaxf(s, -80.f), 80.f);
}

// ---------------------------------------------------------------------------
// QKV precompute. qp/kp: [B][N] rows of 32B = 8 bf16 (d0..7) + 16B zeros
// (zero-pads MFMA K=16; data/zero slots match between A and B operands, so
// this is robust to the exact HW k-slot mapping). vb: [B][C][N] bf16 (V^T).
// Wq/bq pre-scaled by log2e so attention uses raw exp2.
// grid 256 (b x 64 n-tiles of 64), block 128 (2 waves x 32 n).
// ---------------------------------------------------------------------------
__global__ __launch_bounds__(128, 1) void qkv_k(
    const float* __restrict__ x, const float* __restrict__ inf,
    const float* __restrict__ Wq, const float* __restrict__ bq,
    const float* __restrict__ Wk, const float* __restrict__ bk,
    const float* __restrict__ Wv, const float* __restrict__ bv,
    u32* __restrict__ qp, u32* __restrict__ kp, u16* __restrict__ vb)
{
  __shared__ float bias[80];
  const int tid = threadIdx.x;
  if (tid < 64)      bias[tid] = bv[tid];
  else if (tid < 72) bias[tid] = bq[tid-64]*LOG2E;
  else if (tid < 80) bias[tid] = bk[tid-72];
  __syncthreads();
  const int w = tid >> 6, lane = tid & 63, ln = lane & 31, hi = lane >> 5;
  const int b  = blockIdx.x >> 6;
  const int n0 = (blockIdx.x & 63)*64 + w*32;
  const int n  = n0 + ln;

  // A-frags: Wv rows (2 m-tiles), W2 = [Wq*log2e ; Wk ; zeros] rows.
  bf16x8 wvf[2][4];
#pragma unroll
  for (int mt = 0; mt < 2; ++mt)
#pragma unroll
    for (int ks = 0; ks < 4; ++ks){
      const float* s = Wv + (mt*32+ln)*64 + ks*16 + hi*8;
      wvf[mt][ks] = pack8(s[0],s[1],s[2],s[3],s[4],s[5],s[6],s[7]);
    }
  bf16x8 w2f[4];
#pragma unroll
  for (int ks = 0; ks < 4; ++ks){
    float t[8];
#pragma unroll
    for (int i = 0; i < 8; ++i){
      float v = 0.f;
      if (ln < 8)       v = Wq[ln*64 + ks*16 + hi*8 + i]*LOG2E;
      else if (ln < 16) v = Wk[(ln-8)*64 + ks*16 + hi*8 + i];
      t[i] = v;
    }
    w2f[ks] = pack8(t[0],t[1],t[2],t[3],t[4],t[5],t[6],t[7]);
  }

  f32x16 dqk = {}; f32x16 dv0 = {}; f32x16 dv1 = {};
#pragma unroll
  for (int ks = 0; ks < 4; ++ks){
    const float* ip = inf + (size_t)(b*64 + ks*16 + hi*8)*4096 + n;
    bf16x8 bi = pack8(ip[0], ip[4096], ip[2*4096], ip[3*4096],
                      ip[4*4096], ip[5*4096], ip[6*4096], ip[7*4096]);
    dqk = mfma32(w2f[ks], bi, dqk);
    const float* xp = x + (size_t)(b*64 + ks*16 + hi*8)*4096 + n;
    bf16x8 bx = pack8(xp[0], xp[4096], xp[2*4096], xp[3*4096],
                      xp[4*4096], xp[5*4096], xp[6*4096], xp[7*4096]);
    dv0 = mfma32(wvf[0][ks], bx, dv0);
    dv1 = mfma32(wvf[1][ks], bx, dv1);
  }
  // D rows: r0-3 -> q d=4hi+r, r4-7 -> k d=4hi+(r-4); rows>=16 discarded.
  {
    u32 q0 = pk2(dqk[0]+bias[64+4*hi+0], dqk[1]+bias[64+4*hi+1]);
    u32 q1 = pk2(dqk[2]+bias[64+4*hi+2], dqk[3]+bias[64+4*hi+3]);
    u32 k0 = pk2(dqk[4]+bias[72+4*hi+0], dqk[5]+bias[72+4*hi+1]);
    u32 k1 = pk2(dqk[6]+bias[72+4*hi+2], dqk[7]+bias[72+4*hi+3]);
    u32* qd = qp + (size_t)(b*4096 + n)*8 + hi*2;   // hi=0: words 0,1,4,5
    qd[0] = q0; qd[1] = q1; qd[4] = 0u; qd[5] = 0u; // hi=1: words 2,3,6,7
    u32* kd = kp + (size_t)(b*4096 + n)*8 + hi*2;
    kd[0] = k0; kd[1] = k1; kd[4] = 0u; kd[5] = 0u;
  }
#pragma unroll
  for (int mt = 0; mt < 2; ++mt){
    const f32x16 dv = mt ? dv1 : dv0;
#pragma unroll
    for (int r = 0; r < 16; ++r){
      const int c = mt*32 + (r&3) + 8*(r>>2) + 4*hi;
      vb[(size_t)(b*64 + c)*4096 + n] = (u16)bfr(dv[r] + bias[c]);
    }
  }
}

// ---------------------------------------------------------------------------
// Fused attention, wave-private key-split, barrier-ordered staging.
// grid 512: b = blk>>7, mt = blk&127 (32 q-rows). block 256 = 4 waves.
// LDS per wave (10240 B): K 2048 (64 rows x 32B) | V 8192 (64 c x 128B, swz).
// Epilogue reuses the same region: acc f32[64][32] (8192B) + rs[32].
// ---------------------------------------------------------------------------
__global__ __launch_bounds__(256, 2) void attn_k(
    const u32* __restrict__ qp, const u32* __restrict__ kp, const u16* __restrict__ vb,
    const float* __restrict__ x, const float* __restrict__ gamma,
    float* __restrict__ out)
{
  __shared__ __align__(16) char smem[40960];
  const int tid = threadIdx.x, w = tid >> 6, lane = tid & 63, ln = lane & 31, hi = lane >> 5;
  const int b = blockIdx.x >> 7, mt = blockIdx.x & 127;
  const int m0 = mt * 32;
  char* const base = smem + w*10240;

  const bf16x8 qf = *(const bf16x8*)(qp + (size_t)(b*4096 + m0 + ln)*8 + hi*4);

  // staging sources (per-lane): K row = lane (32B); V rows c = i*8 + (lane>>3)
  const char* kptr = (const char*)kp + (size_t)(b*4096 + w*1024)*32 + lane*32;
  const char* vptr = (const char*)vb + ((size_t)(b*64 + (lane>>3))*4096 + w*1024)*2
                     + (lane&7)*16;
  const int vds = (lane>>3)*128 + (((lane&7)*16) ^ ((lane>>3)<<4));  // swz write addr

  u32x4 kst0, kst1, vst0, vst1, vst2, vst3, vst4, vst5, vst6, vst7;
#define LOADJ                                                 \
  kst0 = *(const u32x4*)(kptr); kst1 = *(const u32x4*)(kptr+16); \
  vst0 = *(const u32x4*)(vptr);           vst1 = *(const u32x4*)(vptr+65536);   \
  vst2 = *(const u32x4*)(vptr+2*65536);   vst3 = *(const u32x4*)(vptr+3*65536); \
  vst4 = *(const u32x4*)(vptr+4*65536);   vst5 = *(const u32x4*)(vptr+5*65536); \
  vst6 = *(const u32x4*)(vptr+6*65536);   vst7 = *(const u32x4*)(vptr+7*65536)
#define WRITEJ                                                 \
  *(u32x4*)(base + lane*32) = kst0; *(u32x4*)(base + lane*32 + 16) = kst1;     \
  { char* vB_ = base + 2048 + vds;                                             \
    *(u32x4*)(vB_)        = vst0; *(u32x4*)(vB_ + 1024) = vst1;                \
    *(u32x4*)(vB_ + 2048) = vst2; *(u32x4*)(vB_ + 3072) = vst3;                \
    *(u32x4*)(vB_ + 4096) = vst4; *(u32x4*)(vB_ + 5120) = vst5;                \
    *(u32x4*)(vB_ + 6144) = vst6; *(u32x4*)(vB_ + 7168) = vst7; }

  LOADJ;                                            // chunk 0 -> regs

  f32x16 acc0 = {}; f32x16 acc1 = {};
  float rs = 0.f;

  for (int j = 0; j < 16; ++j){
    WRITEJ;                                         // regs -> LDS (own region)
    if (j < 15){ kptr += 2048; vptr += 128; LOADJ; }// prefetch next chunk (T14)
    __syncthreads();                                // staging visible (HW-ordered)

    const bf16x8 ka0 = lds_frag(base + ln*32 + hi*16);
    const bf16x8 ka1 = lds_frag(base + 1024 + ln*32 + hi*16);
    const f32x16 z = {};
    const f32x16 st0 = mfma32(ka0, qf, z);  // S^T[key][m=ln], key=(r&3)+8(r>>2)+4hi
    const f32x16 st1 = mfma32(ka1, qf, z);

    float p0[16], p1[16];
#pragma unroll
    for (int r = 0; r < 16; ++r) p0[r] = EXP2(sclamp(st0[r]));
#pragma unroll
    for (int r = 0; r < 16; ++r) p1[r] = EXP2(sclamp(st1[r]));
    float t0 = 0.f, t1 = 0.f;
#pragma unroll
    for (int r = 0; r < 16; ++r){ t0 += p0[r]; t1 += p1[r]; }
    rs += t0 + t1;

    // Repack P^T into PV B-fragments with shfl_xor(32) + select (no asm).
    // word w of slot holds keys {2w,2w+1} + 8*hi within each 16-key group.
    bf16x8 b2[4];
#pragma unroll
    for (int g = 0; g < 4; ++g){
      const float* pp = (g & 2) ? p1 : p0;
      const int o = (g & 1) * 8;
      u32 x0 = pk2(pp[o+0], pp[o+1]), x1 = pk2(pp[o+2], pp[o+3]);
      u32 x2 = pk2(pp[o+4], pp[o+5]), x3 = pk2(pp[o+6], pp[o+7]);
      u32 s0 = __shfl_xor(x0, 32), s1 = __shfl_xor(x1, 32);
      u32 s2 = __shfl_xor(x2, 32), s3 = __shfl_xor(x3, 32);
      b2[g] = mk_frag(hi ? s2 : x0, hi ? s3 : x1,
                      hi ? x2 : s0, hi ? x3 : s1);
    }

    const char* vB = base + 2048;
    const int sw = (ln & 7) << 4;
#pragma unroll
    for (int ks = 0; ks < 4; ++ks){
      const bf16x8 vf0 = lds_frag(vB + ln*128 + ((ks*32 + hi*16) ^ sw));
      acc0 = mfma32(vf0, b2[ks], acc0);
      const bf16x8 vf1 = lds_frag(vB + (32+ln)*128 + ((ks*32 + hi*16) ^ sw));
      acc1 = mfma32(vf1, b2[ks], acc1);
    }
    __syncthreads();                                // all reads done before next WRITEJ
  }
#undef LOADJ
#undef WRITEJ

  const float rt = rs + __shfl_xor(rs, 32);         // full 1024-key sum, m=ln

  // publish this wave's partials into its own region: [64 c][32 m] f32 + rs[32]
  float* accS = (float*)base;
#pragma unroll
  for (int r = 0; r < 16; ++r){
    const int c = (r&3) + 8*(r>>2) + 4*hi;
    accS[c*32 + ln]      = acc0[r];
    accS[(32+c)*32 + ln] = acc1[r];
  }
  if (lane < 32) ((float*)(base + 8192))[ln] = rt;
  __syncthreads();

  // each wave reduces c-range [w*16, w*16+16) and writes final output
  const float g = gamma[0];
  float rtot = 0.f;
#pragma unroll
  for (int ww = 0; ww < 4; ++ww)
    rtot += ((const float*)(smem + ww*10240 + 8192))[ln];
  const float rinv = g / rtot;
#pragma unroll
  for (int i = 0; i < 8; ++i){
    const int c = w*16 + hi*8 + i;
    float s = 0.f;
#pragma unroll
    for (int ww = 0; ww < 4; ++ww)
      s += ((const float*)(smem + ww*10240))[c*32 + ln];
    const size_t o = (size_t)(b*64 + c)*4096 + m0 + ln;
    out[o] = s * rinv + x[o];
  }
}

extern "C" void kernel_launch(void* const* d_in, const int* in_sizes, int n_in,
                              void* d_out, int out_size, void* d_ws, size_t ws_size,
                              hipStream_t stream)
{
  (void)in_sizes; (void)n_in; (void)out_size; (void)ws_size;
  const float* x   = (const float*)d_in[0];
  const float* inf = (const float*)d_in[1];
  const float* Wq  = (const float*)d_in[2];
  const float* bq  = (const float*)d_in[3];
  const float* Wk  = (const float*)d_in[4];
  const float* bk  = (const float*)d_in[5];
  const float* Wv  = (const float*)d_in[6];
  const float* bv  = (const float*)d_in[7];
  const float* gm  = (const float*)d_in[8];
  float* out = (float*)d_out;

  char* ws = (char*)d_ws;                 // 3.07 MB used
  u32* qp = (u32*)(ws);                   // 524288 B
  u32* kp = (u32*)(ws + 524288);          // 524288 B
  u16* vb = (u16*)(ws + 1048576);         // 2097152 B

  qkv_k<<<dim3(256), dim3(128), 0, stream>>>(x, inf, Wq, bq, Wk, bk, Wv, bv, qp, kp, vb);
  attn_k<<<dim3(512), dim3(256), 0, stream>>>(qp, kp, vb, x, gm, out);
}

// Round 8
// 112.986 us; speedup vs baseline: 1.0449x; 1.0449x over previous
//
#include <hip/hip_runtime.h>
#include <hip/hip_bf16.h>
#include <stdint.h>

// InfPamAtt fused attention, MI355X/gfx950.  Round 8: resubmission of the
// round-7 occupancy-2x kernel (broker timeout -> no signal; audit-clean).
// Green round-6 structure kept (C-level bf16 pack, shfl repack, clamp,
// barrier-ordered V staging). Changes vs round 6:
//   - attn_k: 8 waves x 512 keys per block (512 thr) instead of 4 x 1024
//     -> 4096 waves = 16/CU (was 8/CU). LDS 64KB (8 x 8KB V regions).
//   - K staging removed from LDS: kp's packed layout makes K fragments
//     per-lane contiguous coalesced 16B global loads (LDS transpose was
//     only needed for V). K frags prefetched one chunk ahead.
//   qkv_k : unchanged (known-good).
// Workspace: qp 512K | kp 512K | vb 2M = 3.07 MB.

typedef float    f32x16 __attribute__((ext_vector_type(16)));
typedef short    bf16x8 __attribute__((ext_vector_type(8)));
typedef unsigned int   u32;
typedef unsigned short u16;
typedef u32 u32x4 __attribute__((ext_vector_type(4)));

#define LOG2E 1.4426950408889634f

// f32 -> bf16 bits (round-to-nearest-even), result in low 16 bits. Pure C.
__device__ __forceinline__ u32 bfr(float f){
  u32 u = __float_as_uint(f);
  return (u + 0x7FFFu + ((u >> 16) & 1u)) >> 16;
}
__device__ __forceinline__ u32 pk2(float lo, float hi){
  return bfr(lo) | (bfr(hi) << 16);
}
__device__ __forceinline__ bf16x8 mk_frag(u32 a, u32 b, u32 c, u32 d){
  union { u32 u[4]; bf16x8 v; } t; t.u[0]=a; t.u[1]=b; t.u[2]=c; t.u[3]=d; return t.v;
}
__device__ __forceinline__ bf16x8 pack8(float t0,float t1,float t2,float t3,
                                        float t4,float t5,float t6,float t7){
  return mk_frag(pk2(t0,t1), pk2(t2,t3), pk2(t4,t5), pk2(t6,t7));
}
__device__ __forceinline__ f32x16 mfma32(bf16x8 a, bf16x8 b, f32x16 c){
  return __builtin_amdgcn_mfma_f32_32x32x16_bf16(a, b, c, 0, 0, 0);
}
// 16B load reinterpreted as a bf16x8 fragment (u32x4 access type everywhere).
__device__ __forceinline__ bf16x8 frag16(const char* p){
  union { u32x4 u; bf16x8 f; } t; t.u = *(const u32x4*)p; return t.f;
}
#if __has_builtin(__builtin_amdgcn_exp2f)
#define EXP2(x) __builtin_amdgcn_exp2f(x)
#else
#define EXP2(x) exp2f(x)
#endif
// Two-sided clamp: sanitizes NaN and bounds exp2 to [2^-80, 2^80] -> rowsum
// strictly positive & finite. Keeps failure modes diagnostic.
__device__ __forceinline__ float sclamp(float s){
  return fminf(fmaxf(s, -80.f), 80.f);
}

// ---------------------------------------------------------------------------
// QKV precompute (UNCHANGED from green round 6).
// qp/kp: [B][N] rows of 32B = 8 bf16 (d0..7) + 16B zeros. vb: [B][C][N] bf16.
// Wq/bq pre-scaled by log2e so attention uses raw exp2.
// grid 256 (b x 64 n-tiles of 64), block 128 (2 waves x 32 n).
// ---------------------------------------------------------------------------
__global__ __launch_bounds__(128, 1) void qkv_k(
    const float* __restrict__ x, const float* __restrict__ inf,
    const float* __restrict__ Wq, const float* __restrict__ bq,
    const float* __restrict__ Wk, const float* __restrict__ bk,
    const float* __restrict__ Wv, const float* __restrict__ bv,
    u32* __restrict__ qp, u32* __restrict__ kp, u16* __restrict__ vb)
{
  __shared__ float bias[80];
  const int tid = threadIdx.x;
  if (tid < 64)      bias[tid] = bv[tid];
  else if (tid < 72) bias[tid] = bq[tid-64]*LOG2E;
  else if (tid < 80) bias[tid] = bk[tid-72];
  __syncthreads();
  const int w = tid >> 6, lane = tid & 63, ln = lane & 31, hi = lane >> 5;
  const int b  = blockIdx.x >> 6;
  const int n0 = (blockIdx.x & 63)*64 + w*32;
  const int n  = n0 + ln;

  bf16x8 wvf[2][4];
#pragma unroll
  for (int mt = 0; mt < 2; ++mt)
#pragma unroll
    for (int ks = 0; ks < 4; ++ks){
      const float* s = Wv + (mt*32+ln)*64 + ks*16 + hi*8;
      wvf[mt][ks] = pack8(s[0],s[1],s[2],s[3],s[4],s[5],s[6],s[7]);
    }
  bf16x8 w2f[4];
#pragma unroll
  for (int ks = 0; ks < 4; ++ks){
    float t[8];
#pragma unroll
    for (int i = 0; i < 8; ++i){
      float v = 0.f;
      if (ln < 8)       v = Wq[ln*64 + ks*16 + hi*8 + i]*LOG2E;
      else if (ln < 16) v = Wk[(ln-8)*64 + ks*16 + hi*8 + i];
      t[i] = v;
    }
    w2f[ks] = pack8(t[0],t[1],t[2],t[3],t[4],t[5],t[6],t[7]);
  }

  f32x16 dqk = {}; f32x16 dv0 = {}; f32x16 dv1 = {};
#pragma unroll
  for (int ks = 0; ks < 4; ++ks){
    const float* ip = inf + (size_t)(b*64 + ks*16 + hi*8)*4096 + n;
    bf16x8 bi = pack8(ip[0], ip[4096], ip[2*4096], ip[3*4096],
                      ip[4*4096], ip[5*4096], ip[6*4096], ip[7*4096]);
    dqk = mfma32(w2f[ks], bi, dqk);
    const float* xp = x + (size_t)(b*64 + ks*16 + hi*8)*4096 + n;
    bf16x8 bx = pack8(xp[0], xp[4096], xp[2*4096], xp[3*4096],
                      xp[4*4096], xp[5*4096], xp[6*4096], xp[7*4096]);
    dv0 = mfma32(wvf[0][ks], bx, dv0);
    dv1 = mfma32(wvf[1][ks], bx, dv1);
  }
  {
    u32 q0 = pk2(dqk[0]+bias[64+4*hi+0], dqk[1]+bias[64+4*hi+1]);
    u32 q1 = pk2(dqk[2]+bias[64+4*hi+2], dqk[3]+bias[64+4*hi+3]);
    u32 k0 = pk2(dqk[4]+bias[72+4*hi+0], dqk[5]+bias[72+4*hi+1]);
    u32 k1 = pk2(dqk[6]+bias[72+4*hi+2], dqk[7]+bias[72+4*hi+3]);
    u32* qd = qp + (size_t)(b*4096 + n)*8 + hi*2;   // hi=0: words 0,1,4,5
    qd[0] = q0; qd[1] = q1; qd[4] = 0u; qd[5] = 0u; // hi=1: words 2,3,6,7
    u32* kd = kp + (size_t)(b*4096 + n)*8 + hi*2;
    kd[0] = k0; kd[1] = k1; kd[4] = 0u; kd[5] = 0u;
  }
#pragma unroll
  for (int mt = 0; mt < 2; ++mt){
    const f32x16 dv = mt ? dv1 : dv0;
#pragma unroll
    for (int r = 0; r < 16; ++r){
      const int c = mt*32 + (r&3) + 8*(r>>2) + 4*hi;
      vb[(size_t)(b*64 + c)*4096 + n] = (u16)bfr(dv[r] + bias[c]);
    }
  }
}

// ---------------------------------------------------------------------------
// Fused attention. grid 512: b = blk>>7, mt = blk&127 (32 q-rows).
// block 512 = 8 waves; wave w owns keys [w*512,(w+1)*512) in 8 chunks of 64.
// Per-wave LDS: V tile only (8KB, 64c x 128B swizzled). K frags direct-from-
// global (coalesced 16B/lane from kp packed layout), prefetched 1 ahead.
// Epilogue: rs pre-pass exchange, then acc publish + 8-region reduce.
// ---------------------------------------------------------------------------
__global__ __launch_bounds__(512, 4) void attn_k(
    const u32* __restrict__ qp, const u32* __restrict__ kp, const u16* __restrict__ vb,
    const float* __restrict__ x, const float* __restrict__ gamma,
    float* __restrict__ out)
{
  __shared__ __align__(16) char smem[65536];       // 8 x 8KB wave V regions
  const int tid = threadIdx.x, w = tid >> 6, lane = tid & 63, ln = lane & 31, hi = lane >> 5;
  const int b = blockIdx.x >> 7, mt = blockIdx.x & 127;
  const int m0 = mt * 32;
  char* const base = smem + w*8192;

  const bf16x8 qf = *(const bf16x8*)(qp + (size_t)(b*4096 + m0 + ln)*8 + hi*4);

  // V staging source (per-lane): rows c = i*8 + (lane>>3), 16B each, coalesced.
  const char* vptr = (const char*)vb + ((size_t)(b*64 + (lane>>3))*4096 + w*512)*2
                     + (lane&7)*16;
  const int vds = (lane>>3)*128 + (((lane&7)*16) ^ ((lane>>3)<<4));  // swz write addr
  // K fragment source (per-lane, contiguous 16B, coalesced): row = chunk base + ln.
  const char* kb = (const char*)kp + (size_t)(b*4096 + w*512)*32 + ln*32 + hi*16;

  u32x4 vst0, vst1, vst2, vst3, vst4, vst5, vst6, vst7;
#define LOADV                                                 \
  vst0 = *(const u32x4*)(vptr);           vst1 = *(const u32x4*)(vptr+65536);   \
  vst2 = *(const u32x4*)(vptr+2*65536);   vst3 = *(const u32x4*)(vptr+3*65536); \
  vst4 = *(const u32x4*)(vptr+4*65536);   vst5 = *(const u32x4*)(vptr+5*65536); \
  vst6 = *(const u32x4*)(vptr+6*65536);   vst7 = *(const u32x4*)(vptr+7*65536)
#define WRITEV                                                 \
  { char* vB_ = base + vds;                                                    \
    *(u32x4*)(vB_)        = vst0; *(u32x4*)(vB_ + 1024) = vst1;                \
    *(u32x4*)(vB_ + 2048) = vst2; *(u32x4*)(vB_ + 3072) = vst3;                \
    *(u32x4*)(vB_ + 4096) = vst4; *(u32x4*)(vB_ + 5120) = vst5;                \
    *(u32x4*)(vB_ + 6144) = vst6; *(u32x4*)(vB_ + 7168) = vst7; }

  LOADV;                                           // V chunk 0 -> regs
  bf16x8 ka0 = frag16(kb);                         // K chunk 0 frags
  bf16x8 ka1 = frag16(kb + 1024);

  f32x16 acc0 = {}; f32x16 acc1 = {};
  float rs = 0.f;

  for (int j = 0; j < 8; ++j){
    WRITEV;                                        // regs -> LDS (own region)
    if (j < 7){ vptr += 128; LOADV; }              // prefetch next V (T14)
    __syncthreads();                               // staging visible

    const f32x16 z = {};
    const f32x16 st0 = mfma32(ka0, qf, z);  // S^T[key][m=ln], key=(r&3)+8(r>>2)+4hi
    const f32x16 st1 = mfma32(ka1, qf, z);
    if (j < 7){ kb += 2048; ka0 = frag16(kb); ka1 = frag16(kb + 1024); } // prefetch K

    float p0[16], p1[16];
#pragma unroll
    for (int r = 0; r < 16; ++r) p0[r] = EXP2(sclamp(st0[r]));
#pragma unroll
    for (int r = 0; r < 16; ++r) p1[r] = EXP2(sclamp(st1[r]));
    float t0 = 0.f, t1 = 0.f;
#pragma unroll
    for (int r = 0; r < 16; ++r){ t0 += p0[r]; t1 += p1[r]; }
    rs += t0 + t1;

    // Repack P^T into PV B-fragments with shfl_xor(32) + select (no asm).
    bf16x8 b2[4];
#pragma unroll
    for (int g = 0; g < 4; ++g){
      const float* pp = (g & 2) ? p1 : p0;
      const int o = (g & 1) * 8;
      u32 x0 = pk2(pp[o+0], pp[o+1]), x1 = pk2(pp[o+2], pp[o+3]);
      u32 x2 = pk2(pp[o+4], pp[o+5]), x3 = pk2(pp[o+6], pp[o+7]);
      u32 s0 = __shfl_xor(x0, 32), s1 = __shfl_xor(x1, 32);
      u32 s2 = __shfl_xor(x2, 32), s3 = __shfl_xor(x3, 32);
      b2[g] = mk_frag(hi ? s2 : x0, hi ? s3 : x1,
                      hi ? x2 : s0, hi ? x3 : s1);
    }

    const int sw = (ln & 7) << 4;
#pragma unroll
    for (int ks = 0; ks < 4; ++ks){
      const bf16x8 vf0 = frag16(base + ln*128 + ((ks*32 + hi*16) ^ sw));
      acc0 = mfma32(vf0, b2[ks], acc0);
      const bf16x8 vf1 = frag16(base + (32+ln)*128 + ((ks*32 + hi*16) ^ sw));
      acc1 = mfma32(vf1, b2[ks], acc1);
    }
    __syncthreads();                               // V reads done before next WRITEV
  }
#undef LOADV
#undef WRITEV

  const float rt = rs + __shfl_xor(rs, 32);        // this wave's 512-key sum, m=ln

  // rs pre-pass exchange (1KB scratch in wave 0's region; all loop reads done)
  __syncthreads();
  if (lane < 32) ((float*)smem)[w*32 + ln] = rt;
  __syncthreads();
  float rtot = 0.f;
#pragma unroll
  for (int ww = 0; ww < 8; ++ww)
    rtot += ((const float*)smem)[ww*32 + ln];
  const float rinv = gamma[0] / rtot;
  __syncthreads();                                 // rs reads done before publish

  // publish acc into own region: [64 c][32 m] f32 = 8KB
  float* accS = (float*)base;
#pragma unroll
  for (int r = 0; r < 16; ++r){
    const int c = (r&3) + 8*(r>>2) + 4*hi;
    accS[c*32 + ln]      = acc0[r];
    accS[(32+c)*32 + ln] = acc1[r];
  }
  __syncthreads();

  // wave w reduces c-range [w*8, w*8+8) and writes final output
#pragma unroll
  for (int i = 0; i < 4; ++i){
    const int c = w*8 + hi*4 + i;
    float s = 0.f;
#pragma unroll
    for (int ww = 0; ww < 8; ++ww)
      s += ((const float*)(smem + ww*8192))[c*32 + ln];
    const size_t o = (size_t)(b*64 + c)*4096 + m0 + ln;
    out[o] = s * rinv + x[o];
  }
}

extern "C" void kernel_launch(void* const* d_in, const int* in_sizes, int n_in,
                              void* d_out, int out_size, void* d_ws, size_t ws_size,
                              hipStream_t stream)
{
  (void)in_sizes; (void)n_in; (void)out_size; (void)ws_size;
  const float* x   = (const float*)d_in[0];
  const float* inf = (const float*)d_in[1];
  const float* Wq  = (const float*)d_in[2];
  const float* bq  = (const float*)d_in[3];
  const float* Wk  = (const float*)d_in[4];
  const float* bk  = (const float*)d_in[5];
  const float* Wv  = (const float*)d_in[6];
  const float* bv  = (const float*)d_in[7];
  const float* gm  = (const float*)d_in[8];
  float* out = (float*)d_out;

  char* ws = (char*)d_ws;                 // 3.07 MB used
  u32* qp = (u32*)(ws);                   // 524288 B
  u32* kp = (u32*)(ws + 524288);          // 524288 B
  u16* vb = (u16*)(ws + 1048576);         // 2097152 B

  qkv_k<<<dim3(256), dim3(128), 0, stream>>>(x, inf, Wq, bq, Wk, bk, Wv, bv, qp, kp, vb);
  attn_k<<<dim3(512), dim3(512), 0, stream>>>(qp, kp, vb, x, gm, out);
}

// Round 11
// 108.553 us; speedup vs baseline: 1.0875x; 1.0408x over previous
//
#include <hip/hip_runtime.h>
#include <hip/hip_bf16.h>
#include <stdint.h>

// InfPamAtt fused attention, MI355X/gfx950.  Round 11: resubmission of
// round 10 (broker timeout -> no signal; audit-clean).
// ERRATA: rounds 2-5,9 all NaN'd and ALL shared inline-asm v_cvt_pk_bf16_f32;
// green rounds 6,8 used C-level RNE. => the asm is the corruption source
// (T12 caveat: "don't hand-write cvt_pk"). This build uses compiler
// __float2bfloat16 (RNE) everywhere; no inline asm at all.
// Deltas vs green round 8:
//   attn_k: compiler-cast pk2 (repack diet), clamp -> one-sided fminf(s,30).
//   qkv_k : re-tiled for occupancy: grid 512 (32-n tiles) x 2 role-split
//           waves (w0: Q/K, w1: V) -> 2x waves/CU, 32 loads/wave (was 64).
// Workspace: qp 512K | kp 512K | vb 2M = 3.07 MB.

typedef float    f32x16 __attribute__((ext_vector_type(16)));
typedef short    bf16x8 __attribute__((ext_vector_type(8)));
typedef unsigned int   u32;
typedef unsigned short u16;
typedef u32 u32x4 __attribute__((ext_vector_type(4)));

#define LOG2E 1.4426950408889634f

// f32 -> bf16 via compiler (RNE; fptrunc->HW cvt on gfx950).
__device__ __forceinline__ u16 bf1(float f){
  union { __hip_bfloat16 h; u16 u; } t; t.h = __float2bfloat16(f); return t.u;
}
__device__ __forceinline__ u32 pk2(float lo, float hi){
  return (u32)bf1(lo) | ((u32)bf1(hi) << 16);
}
__device__ __forceinline__ bf16x8 mk_frag(u32 a, u32 b, u32 c, u32 d){
  union { u32 u[4]; bf16x8 v; } t; t.u[0]=a; t.u[1]=b; t.u[2]=c; t.u[3]=d; return t.v;
}
__device__ __forceinline__ bf16x8 pack8(float t0,float t1,float t2,float t3,
                                        float t4,float t5,float t6,float t7){
  return mk_frag(pk2(t0,t1), pk2(t2,t3), pk2(t4,t5), pk2(t6,t7));
}
__device__ __forceinline__ f32x16 mfma32(bf16x8 a, bf16x8 b, f32x16 c){
  return __builtin_amdgcn_mfma_f32_32x32x16_bf16(a, b, c, 0, 0, 0);
}
// 16B load reinterpreted as a bf16x8 fragment (u32x4 access type everywhere).
__device__ __forceinline__ bf16x8 frag16(const char* p){
  union { u32x4 u; bf16x8 f; } t; t.u = *(const u32x4*)p; return t.f;
}
#if __has_builtin(__builtin_amdgcn_exp2f)
#define EXP2(x) __builtin_amdgcn_exp2f(x)
#else
#define EXP2(x) exp2f(x)
#endif
// One-sided cap: prevents exp2 overflow-NaN from any upstream garbage
// (fminf(NaN,30)=30) at 1 VALU op. Correct data has |S| <~ 5.
__device__ __forceinline__ float scap(float s){ return fminf(s, 30.f); }

// ---------------------------------------------------------------------------
// QKV precompute, role-split re-tiling.
// qp/kp: [B][N] rows of 32B = 8 bf16 (d0..7) + 16B zeros. vb: [B][C][N] bf16.
// Wq/bq pre-scaled by log2e so attention uses raw exp2.
// grid 512 (b x 128 n-tiles of 32), block 128 = 2 waves:
//   wave 0: dqk (4 MFMA, 32 inf-frag loads) -> qp/kp
//   wave 1: dv0+dv1 (8 MFMA, 32 x-frag loads) -> vb
// ---------------------------------------------------------------------------
__global__ __launch_bounds__(128, 1) void qkv_k(
    const float* __restrict__ x, const float* __restrict__ inf,
    const float* __restrict__ Wq, const float* __restrict__ bq,
    const float* __restrict__ Wk, const float* __restrict__ bk,
    const float* __restrict__ Wv, const float* __restrict__ bv,
    u32* __restrict__ qp, u32* __restrict__ kp, u16* __restrict__ vb)
{
  __shared__ float bias[80];
  const int tid = threadIdx.x;
  if (tid < 64)      bias[tid] = bv[tid];
  else if (tid < 72) bias[tid] = bq[tid-64]*LOG2E;
  else if (tid < 80) bias[tid] = bk[tid-72];
  __syncthreads();
  const int w = tid >> 6, lane = tid & 63, ln = lane & 31, hi = lane >> 5;
  const int b = blockIdx.x >> 7;
  const int n = (blockIdx.x & 127)*32 + ln;

  if (w == 0){
    // ---- Q/K wave: W2 = [Wq*log2e ; Wk ; zeros] rows ----
    bf16x8 w2f[4];
#pragma unroll
    for (int ks = 0; ks < 4; ++ks){
      float t[8];
#pragma unroll
      for (int i = 0; i < 8; ++i){
        float v = 0.f;
        if (ln < 8)       v = Wq[ln*64 + ks*16 + hi*8 + i]*LOG2E;
        else if (ln < 16) v = Wk[(ln-8)*64 + ks*16 + hi*8 + i];
        t[i] = v;
      }
      w2f[ks] = pack8(t[0],t[1],t[2],t[3],t[4],t[5],t[6],t[7]);
    }
    f32x16 dqk = {};
#pragma unroll
    for (int ks = 0; ks < 4; ++ks){
      const float* ip = inf + (size_t)(b*64 + ks*16 + hi*8)*4096 + n;
      bf16x8 bi = pack8(ip[0], ip[4096], ip[2*4096], ip[3*4096],
                        ip[4*4096], ip[5*4096], ip[6*4096], ip[7*4096]);
      dqk = mfma32(w2f[ks], bi, dqk);
    }
    // D rows: r0-3 -> q d=4hi+r, r4-7 -> k d=4hi+(r-4); rows>=16 discarded.
    u32 q0 = pk2(dqk[0]+bias[64+4*hi+0], dqk[1]+bias[64+4*hi+1]);
    u32 q1 = pk2(dqk[2]+bias[64+4*hi+2], dqk[3]+bias[64+4*hi+3]);
    u32 k0 = pk2(dqk[4]+bias[72+4*hi+0], dqk[5]+bias[72+4*hi+1]);
    u32 k1 = pk2(dqk[6]+bias[72+4*hi+2], dqk[7]+bias[72+4*hi+3]);
    u32* qd = qp + (size_t)(b*4096 + n)*8 + hi*2;   // hi=0: words 0,1,4,5
    qd[0] = q0; qd[1] = q1; qd[4] = 0u; qd[5] = 0u; // hi=1: words 2,3,6,7
    u32* kd = kp + (size_t)(b*4096 + n)*8 + hi*2;
    kd[0] = k0; kd[1] = k1; kd[4] = 0u; kd[5] = 0u;
  } else {
    // ---- V wave: Wv rows, 2 m-tiles ----
    bf16x8 wvf[2][4];
#pragma unroll
    for (int mt = 0; mt < 2; ++mt)
#pragma unroll
      for (int ks = 0; ks < 4; ++ks){
        const float* s = Wv + (mt*32+ln)*64 + ks*16 + hi*8;
        wvf[mt][ks] = pack8(s[0],s[1],s[2],s[3],s[4],s[5],s[6],s[7]);
      }
    f32x16 dv0 = {}; f32x16 dv1 = {};
#pragma unroll
    for (int ks = 0; ks < 4; ++ks){
      const float* xp = x + (size_t)(b*64 + ks*16 + hi*8)*4096 + n;
      bf16x8 bx = pack8(xp[0], xp[4096], xp[2*4096], xp[3*4096],
                        xp[4*4096], xp[5*4096], xp[6*4096], xp[7*4096]);
      dv0 = mfma32(wvf[0][ks], bx, dv0);
      dv1 = mfma32(wvf[1][ks], bx, dv1);
    }
#pragma unroll
    for (int mt = 0; mt < 2; ++mt){
      const f32x16 dv = mt ? dv1 : dv0;
#pragma unroll
      for (int r = 0; r < 16; ++r){
        const int c = mt*32 + (r&3) + 8*(r>>2) + 4*hi;
        vb[(size_t)(b*64 + c)*4096 + n] = bf1(dv[r] + bias[c]);
      }
    }
  }
}

// ---------------------------------------------------------------------------
// Fused attention (green round-8 structure). grid 512: b = blk>>7, mt = blk&127
// (32 q-rows). block 512 = 8 waves; wave w owns keys [w*512,(w+1)*512) in 8
// chunks of 64. Per-wave LDS: V tile only (8KB, 64c x 128B swizzled). K frags
// direct-from-global (coalesced 16B/lane), prefetched 1 ahead.
// Epilogue: rs pre-pass exchange, then acc publish + 8-region reduce.
// ---------------------------------------------------------------------------
__global__ __launch_bounds__(512, 4) void attn_k(
    const u32* __restrict__ qp, const u32* __restrict__ kp, const u16* __restrict__ vb,
    const float* __restrict__ x, const float* __restrict__ gamma,
    float* __restrict__ out)
{
  __shared__ __align__(16) char smem[65536];       // 8 x 8KB wave V regions
  const int tid = threadIdx.x, w = tid >> 6, lane = tid & 63, ln = lane & 31, hi = lane >> 5;
  const int b = blockIdx.x >> 7, mt = blockIdx.x & 127;
  const int m0 = mt * 32;
  char* const base = smem + w*8192;

  const bf16x8 qf = *(const bf16x8*)(qp + (size_t)(b*4096 + m0 + ln)*8 + hi*4);

  // V staging source (per-lane): rows c = i*8 + (lane>>3), 16B each, coalesced.
  const char* vptr = (const char*)vb + ((size_t)(b*64 + (lane>>3))*4096 + w*512)*2
                     + (lane&7)*16;
  const int vds = (lane>>3)*128 + (((lane&7)*16) ^ ((lane>>3)<<4));  // swz write addr
  // K fragment source (per-lane, contiguous 16B, coalesced): row = chunk base + ln.
  const char* kb = (const char*)kp + (size_t)(b*4096 + w*512)*32 + ln*32 + hi*16;

  u32x4 vst0, vst1, vst2, vst3, vst4, vst5, vst6, vst7;
#define LOADV                                                 \
  vst0 = *(const u32x4*)(vptr);           vst1 = *(const u32x4*)(vptr+65536);   \
  vst2 = *(const u32x4*)(vptr+2*65536);   vst3 = *(const u32x4*)(vptr+3*65536); \
  vst4 = *(const u32x4*)(vptr+4*65536);   vst5 = *(const u32x4*)(vptr+5*65536); \
  vst6 = *(const u32x4*)(vptr+6*65536);   vst7 = *(const u32x4*)(vptr+7*65536)
#define WRITEV                                                 \
  { char* vB_ = base + vds;                                                    \
    *(u32x4*)(vB_)        = vst0; *(u32x4*)(vB_ + 1024) = vst1;                \
    *(u32x4*)(vB_ + 2048) = vst2; *(u32x4*)(vB_ + 3072) = vst3;                \
    *(u32x4*)(vB_ + 4096) = vst4; *(u32x4*)(vB_ + 5120) = vst5;                \
    *(u32x4*)(vB_ + 6144) = vst6; *(u32x4*)(vB_ + 7168) = vst7; }

  LOADV;                                           // V chunk 0 -> regs
  bf16x8 ka0 = frag16(kb);                         // K chunk 0 frags
  bf16x8 ka1 = frag16(kb + 1024);

  f32x16 acc0 = {}; f32x16 acc1 = {};
  float rs = 0.f;

  for (int j = 0; j < 8; ++j){
    WRITEV;                                        // regs -> LDS (own region)
    if (j < 7){ vptr += 128; LOADV; }              // prefetch next V (T14)
    __syncthreads();                               // staging visible

    const f32x16 z = {};
    const f32x16 st0 = mfma32(ka0, qf, z);  // S^T[key][m=ln], key=(r&3)+8(r>>2)+4hi
    const f32x16 st1 = mfma32(ka1, qf, z);
    if (j < 7){ kb += 2048; ka0 = frag16(kb); ka1 = frag16(kb + 1024); } // prefetch K

    float p0[16], p1[16];
#pragma unroll
    for (int r = 0; r < 16; ++r) p0[r] = EXP2(scap(st0[r]));
#pragma unroll
    for (int r = 0; r < 16; ++r) p1[r] = EXP2(scap(st1[r]));
    float t0 = 0.f, t1 = 0.f;
#pragma unroll
    for (int r = 0; r < 16; ++r){ t0 += p0[r]; t1 += p1[r]; }
    rs += t0 + t1;

    // Repack P^T into PV B-fragments with shfl_xor(32) + select.
    bf16x8 b2[4];
#pragma unroll
    for (int g = 0; g < 4; ++g){
      const float* pp = (g & 2) ? p1 : p0;
      const int o = (g & 1) * 8;
      u32 x0 = pk2(pp[o+0], pp[o+1]), x1 = pk2(pp[o+2], pp[o+3]);
      u32 x2 = pk2(pp[o+4], pp[o+5]), x3 = pk2(pp[o+6], pp[o+7]);
      u32 s0 = __shfl_xor(x0, 32), s1 = __shfl_xor(x1, 32);
      u32 s2 = __shfl_xor(x2, 32), s3 = __shfl_xor(x3, 32);
      b2[g] = mk_frag(hi ? s2 : x0, hi ? s3 : x1,
                      hi ? x2 : s0, hi ? x3 : s1);
    }

    const int sw = (ln & 7) << 4;
#pragma unroll
    for (int ks = 0; ks < 4; ++ks){
      const bf16x8 vf0 = frag16(base + ln*128 + ((ks*32 + hi*16) ^ sw));
      acc0 = mfma32(vf0, b2[ks], acc0);
      const bf16x8 vf1 = frag16(base + (32+ln)*128 + ((ks*32 + hi*16) ^ sw));
      acc1 = mfma32(vf1, b2[ks], acc1);
    }
    __syncthreads();                               // V reads done before next WRITEV
  }
#undef LOADV
#undef WRITEV

  const float rt = rs + __shfl_xor(rs, 32);        // this wave's 512-key sum, m=ln

  // rs pre-pass exchange (1KB scratch in wave 0's region; all loop reads done)
  __syncthreads();
  if (lane < 32) ((float*)smem)[w*32 + ln] = rt;
  __syncthreads();
  float rtot = 0.f;
#pragma unroll
  for (int ww = 0; ww < 8; ++ww)
    rtot += ((const float*)smem)[ww*32 + ln];
  const float rinv = gamma[0] / rtot;
  __syncthreads();                                 // rs reads done before publish

  // publish acc into own region: [64 c][32 m] f32 = 8KB
  float* accS = (float*)base;
#pragma unroll
  for (int r = 0; r < 16; ++r){
    const int c = (r&3) + 8*(r>>2) + 4*hi;
    accS[c*32 + ln]      = acc0[r];
    accS[(32+c)*32 + ln] = acc1[r];
  }
  __syncthreads();

  // wave w reduces c-range [w*8, w*8+8) and writes final output
#pragma unroll
  for (int i = 0; i < 4; ++i){
    const int c = w*8 + hi*4 + i;
    float s = 0.f;
#pragma unroll
    for (int ww = 0; ww < 8; ++ww)
      s += ((const float*)(smem + ww*8192))[c*32 + ln];
    const size_t o = (size_t)(b*64 + c)*4096 + m0 + ln;
    out[o] = s * rinv + x[o];
  }
}

extern "C" void kernel_launch(void* const* d_in, const int* in_sizes, int n_in,
                              void* d_out, int out_size, void* d_ws, size_t ws_size,
                              hipStream_t stream)
{
  (void)in_sizes; (void)n_in; (void)out_size; (void)ws_size;
  const float* x   = (const float*)d_in[0];
  const float* inf = (const float*)d_in[1];
  const float* Wq  = (const float*)d_in[2];
  const float* bq  = (const float*)d_in[3];
  const float* Wk  = (const float*)d_in[4];
  const float* bk  = (const float*)d_in[5];
  const float* Wv  = (const float*)d_in[6];
  const float* bv  = (const float*)d_in[7];
  const float* gm  = (const float*)d_in[8];
  float* out = (float*)d_out;

  char* ws = (char*)d_ws;                 // 3.07 MB used
  u32* qp = (u32*)(ws);                   // 524288 B
  u32* kp = (u32*)(ws + 524288);          // 524288 B
  u16* vb = (u16*)(ws + 1048576);         // 2097152 B

  qkv_k<<<dim3(512), dim3(128), 0, stream>>>(x, inf, Wq, bq, Wk, bk, Wv, bv, qp, kp, vb);
  attn_k<<<dim3(512), dim3(512), 0, stream>>>(qp, kp, vb, x, gm, out);
}